// Round 10
// baseline (259.480 us; speedup 1.0000x reference)
//
#include <hip/hip_runtime.h>
#include <hip/hip_bf16.h>
#include <math.h>

// ---------------- problem constants ----------------
#define NCN   5000      // customer nodes
#define NTN   10000     // target nodes
#define NEDGE 50000     // edges per direction
#define NLBL  20000     // label edges
#define EPB   64        // edges per block (2 waves x 2 M-tiles x 16)
#define EBLK  784       // blocks per direction (784*64 = 50176)
#define ESLOT 50176     // padded slots per direction
#define MT    2         // M-tiles per wave (32 edges/wave)

typedef _Float16 f16x8 __attribute__((ext_vector_type(8)));
typedef _Float16 f16x4 __attribute__((ext_vector_type(4)));
typedef float    f32x4 __attribute__((ext_vector_type(4)));

#define HSTRIDE 72           // halves per hidT row (64 edges + 8 pad)
#define NSLICE  130          // 128 m2w K-slices + 2 bias slices
#define ZSTR    72           // head z-buffer stride in halves

#define PREPBLK (4 * NSLICE + 4 + 8)          // 532
#define NTBLK   ((NCN + 31) / 32 + (NTN + 31) / 32)   // 157 + 313 = 470

__device__ __forceinline__ void stage16(const _Float16* g, _Float16* l) {
  __builtin_amdgcn_global_load_lds(
      (const __attribute__((address_space(1))) void*)g,
      (__attribute__((address_space(3))) void*)l, 16, 0, 0);
}

// ---------------- CSR count (edge lists are fixed inputs) ----------------
__global__ __launch_bounds__(256) void count_edges(
    const int* __restrict__ dT, const int* __restrict__ dC,
    int* __restrict__ cT, int* __restrict__ cC)
{
  int i = blockIdx.x * 256 + threadIdx.x;
  if (i < NEDGE) atomicAdd(&cT[dT[i]], 1);
  else { int j = i - NEDGE; if (j < NEDGE) atomicAdd(&cC[dC[j]], 1); }
}

// ---------------- mega pre-pass: scan (2 blks) + weight prep + node transform ----
struct MegaArgs {
  const int* cntT; int* offT; const int* cntC; int* offC;
  const float* m2w; const float* m2b; _Float16* outB;
  const float* m1w; const float* m1b; _Float16* outM1;
  const float* w0; const float* b0; const float* w1; const float* b1;
  _Float16* outHead;
  const float* emb0; const int* idx0; const float* ntw0; const float* ntb0; float* hout0;
  const float* emb1; const int* idx1; const float* ntw1; const float* ntb1; float* hout1;
};

__global__ __launch_bounds__(256) void mega_pre(MegaArgs a) {
  __shared__ float s_w[64 * 64];
  __shared__ float s_b[64];
  const int bid = blockIdx.x;
  const int t = threadIdx.x;

  if (bid < 2) {
    // ---- exclusive scan of counts -> offsets (off[n] = total), 256 threads ----
    int* lds = (int*)s_w;
    const int* c = bid ? a.cntC : a.cntT;
    int*       o = bid ? a.offC : a.offT;
    int        n = bid ? NCN : NTN;
    int CH = (n + 255) / 256;
    int base = t * CH;
    int s = 0;
    for (int i = 0; i < CH; ++i) { int idx = base + i; if (idx < n) s += c[idx]; }
    lds[t] = s;
    __syncthreads();
    for (int d = 1; d < 256; d <<= 1) {
      int v = (t >= d) ? lds[t - d] : 0;
      __syncthreads();
      lds[t] += v;
      __syncthreads();
    }
    int run = lds[t] - s;   // exclusive prefix
    for (int i = 0; i < CH; ++i) {
      int idx = base + i;
      if (idx < n) { o[idx] = run; run += c[idx]; }
    }
    if (t == 255) o[n] = lds[255];
    return;
  }

  if (bid < 2 + PREPBLK) {
    // ---- weight prep -> f16 fragment slices ----
    int pb = bid - 2;
    int hi = t >> 6, col = t & 63;
    f16x8 v;
    if (pb < 4 * NSLICE) {
      int p = pb / NSLICE, s = pb % NSLICE;
      const float* w  = a.m2w + p * 64 * 4096;
      const float* bb = a.m2b + p * 4096;
      #pragma unroll
      for (int j = 0; j < 8; ++j) {
        float x;
        if (s < 128) {
          int h = s >> 1, i = (s & 1) * 32 + hi * 8 + j;
          x = w[h * 4096 + i * 64 + col];
        } else {
          int i = (s - 128) * 32 + hi * 8 + j;
          x = bb[i * 64 + col];
        }
        v[j] = (_Float16)x;
      }
      *(f16x8*)(a.outB + ((size_t)(p * NSLICE + s)) * 2048 + t * 8) = v;
    } else if (pb < 4 * NSLICE + 4) {
      int p = pb - 4 * NSLICE;
      #pragma unroll
      for (int j = 0; j < 8; ++j) {
        int i = hi * 8 + j;
        float x = (i < 16) ? a.m1w[p * 1024 + i * 64 + col]
                : (i == 16) ? a.m1b[p * 64 + col] : 0.0f;
        v[j] = (_Float16)x;
      }
      *(f16x8*)(a.outM1 + (size_t)p * 2048 + t * 8) = v;
    } else {
      int s = pb - (4 * NSLICE + 4);
      #pragma unroll
      for (int j = 0; j < 8; ++j) {
        int k = hi * 8 + j;
        float x = 0.0f;
        if (s < 5) {
          int kr = s * 32 + k;
          x = (kr < 144) ? a.w0[kr * 64 + col] : (kr == 144 ? a.b0[col] : 0.0f);
        } else {
          int kr = (s - 5) * 32 + k;
          x = (kr < 64) ? a.w1[kr * 64 + col] : (kr == 64 ? a.b1[col] : 0.0f);
        }
        v[j] = (_Float16)x;
      }
      *(f16x8*)(a.outHead + (size_t)s * 2048 + t * 8) = v;
    }
    return;
  }

  // ---- node transform: 32 nodes/block ----
  {
    int nb  = bid - (2 + PREPBLK);
    int blk0 = (NCN + 31) / 32;
    int dir = (nb >= blk0) ? 1 : 0;
    int lb  = nb - (dir ? blk0 : 0);
    const float* emb = dir ? a.emb1 : a.emb0;
    const int*   idx = dir ? a.idx1 : a.idx0;
    const float* w   = dir ? a.ntw1 : a.ntw0;
    const float* b   = dir ? a.ntb1 : a.ntb0;
    float*       out = dir ? a.hout1 : a.hout0;
    int          n   = dir ? NTN : NCN;

    for (int i = t; i < 4096; i += 256) s_w[i] = w[i];
    if (t < 64) s_b[t] = b[t];
    __syncthreads();
    int wave = t >> 6, lane = t & 63;
    #pragma unroll
    for (int it = 0; it < 8; ++it) {
      int node = lb * 32 + wave * 8 + it;
      if (node >= n) continue;
      float v = emb[idx[node] * 64 + lane];
      float acc = s_b[lane];
      #pragma unroll 8
      for (int i = 0; i < 64; ++i)
        acc = fmaf(__shfl(v, i, 64), s_w[i * 64 + lane], acc);
      out[node * 64 + lane] = acc;
    }
  }
}

__global__ __launch_bounds__(256) void scatter_edges(
    const int* __restrict__ dT, const int* __restrict__ dC,
    const int* __restrict__ oT, const int* __restrict__ oC,
    int* __restrict__ curT, int* __restrict__ curC,
    int* __restrict__ permT, int* __restrict__ permC)
{
  int i = blockIdx.x * 256 + threadIdx.x;
  if (i < NEDGE) {
    int d = dT[i];
    int p = atomicAdd(&curT[d], 1);
    permT[oT[d] + p] = i;
  } else {
    int j = i - NEDGE;
    if (j < NEDGE) {
      int d = dC[j];
      int p = atomicAdd(&curC[d], 1);
      permC[oC[d] + p] = j;
    }
  }
}

// ---- streaming MFMA NNConv: B from L2 into registers, ZERO barriers ----
// 64 edges/block (2 waves x 2 M-tiles), grid 2*EBLK = 1568 -> 12 waves/CU.
struct ConvArgs {
  const float* h_src0; const int* esrc0; const float* ea0;
  const int* perm0; const _Float16* B0; const _Float16* m10; float* msg0;
  const float* h_src1; const int* esrc1; const float* ea1;
  const int* perm1; const _Float16* B1; const _Float16* m11; float* msg1;
};

__global__ __launch_bounds__(128, 3) void conv_stream(ConvArgs a) {
  __shared__ __align__(16) _Float16 s_hidT[64 * HSTRIDE];  // 9.2 KB, wave-private cols
  __shared__ int s_srcn[EPB];
  __shared__ int s_eidx[EPB];

  const int bid = blockIdx.x;
  const int dir = (bid >= EBLK) ? 1 : 0;
  const int eb  = bid - (dir ? EBLK : 0);

  const float*    h_src  = dir ? a.h_src1 : a.h_src0;
  const int*      esrc   = dir ? a.esrc1  : a.esrc0;
  const float*    eattr  = dir ? a.ea1    : a.ea0;
  const int*      eperm  = dir ? a.perm1  : a.perm0;
  const _Float16* Bready = dir ? a.B1     : a.B0;
  const _Float16* m1rdy  = dir ? a.m11    : a.m10;
  float*          msg    = dir ? a.msg1   : a.msg0;

  const int tid  = threadIdx.x;
  const int e0   = eb * EPB;
  const int w    = tid >> 6;
  const int lane = tid & 63;
  const int l15  = lane & 15;
  const int hi   = lane >> 4;
  const int wE   = w * 32;               // wave owns 32 edges
  const int boff = (hi * 64 + l15) * 8;  // halves: lane's B-fragment offset

  // ---- idx gather (wave-private 32-slot region; no barrier needed) ----
  if (lane < 32) {
    int e = eperm[e0 + wE + lane];
    s_eidx[wE + lane] = e;
    s_srcn[wE + lane] = esrc[e];
  }

  // ---- gather hv into registers ----
  f16x8 hv0[MT], hv1[MT];
  #pragma unroll
  for (int m = 0; m < MT; ++m) {
    int el = wE + m * 16 + l15;
    const float* src = h_src + (size_t)s_srcn[el] * 64;
    float4 a0 = *(const float4*)(src + hi * 8);
    float4 a1 = *(const float4*)(src + hi * 8 + 4);
    float4 b0 = *(const float4*)(src + 32 + hi * 8);
    float4 b1 = *(const float4*)(src + 32 + hi * 8 + 4);
    hv0[m] = (f16x8){(_Float16)a0.x,(_Float16)a0.y,(_Float16)a0.z,(_Float16)a0.w,
                     (_Float16)a1.x,(_Float16)a1.y,(_Float16)a1.z,(_Float16)a1.w};
    hv1[m] = (f16x8){(_Float16)b0.x,(_Float16)b0.y,(_Float16)b0.z,(_Float16)b0.w,
                     (_Float16)b1.x,(_Float16)b1.y,(_Float16)b1.z,(_Float16)b1.w};
  }

  // ---- hidden = relu(eattr @ m1w + m1b), m1 B-frags direct from L2 ----
  {
    f16x8 ea[MT];
    #pragma unroll
    for (int m = 0; m < MT; ++m) {
      int e = s_eidx[wE + m * 16 + l15];
      f16x8 v = {};
      if (hi < 2) {
        float4 f0 = *(const float4*)(eattr + (size_t)e * 16 + hi * 8);
        float4 f1 = *(const float4*)(eattr + (size_t)e * 16 + hi * 8 + 4);
        v = (f16x8){(_Float16)f0.x,(_Float16)f0.y,(_Float16)f0.z,(_Float16)f0.w,
                    (_Float16)f1.x,(_Float16)f1.y,(_Float16)f1.z,(_Float16)f1.w};
      } else if (hi == 2) {
        v[0] = (_Float16)1.0f;    // i==16 -> bias row
      }
      ea[m] = v;
    }
    #pragma unroll
    for (int n = 0; n < 4; ++n) {
      f16x8 bm = *(const f16x8*)(m1rdy + n * 128 + boff);
      #pragma unroll
      for (int m = 0; m < MT; ++m) {
        f32x4 hacc = {};
        hacc = __builtin_amdgcn_mfma_f32_16x16x32_f16(ea[m], bm, hacc, 0, 0, 0);
        int h  = n * 16 + l15;
        int e4 = wE + m * 16 + hi * 4;
        f16x4 hval;
        #pragma unroll
        for (int r = 0; r < 4; ++r) hval[r] = (_Float16)fmaxf(hacc[r], 0.0f);
        *(f16x4*)&s_hidT[h * HSTRIDE + e4] = hval;   // wave-private columns
      }
    }
  }

  f32x4 acc[MT][4] = {};

#define LOADP(B0_, B1_, P_)                                                   \
  {                                                                           \
    const _Float16* p0 = Bready + (size_t)(2 * (P_)) * 2048 + boff;           \
    _Pragma("unroll")                                                         \
    for (int n = 0; n < 4; ++n) {                                             \
      B0_[n] = *(const f16x8*)(p0 + n * 128);                                 \
      B1_[n] = *(const f16x8*)(p0 + 2048 + n * 128);                          \
    }                                                                         \
  }

#define COMPP(B0_, B1_, P_)                                                   \
  {                                                                           \
    _Float16 hh[MT];                                                          \
    _Pragma("unroll")                                                         \
    for (int m = 0; m < MT; ++m)                                              \
      hh[m] = s_hidT[(P_) * HSTRIDE + wE + m * 16 + l15];                     \
    _Pragma("unroll")                                                         \
    for (int m = 0; m < MT; ++m) {                                            \
      f16x8 av = (f16x8)(hv0[m] * hh[m]);                                     \
      acc[m][0] = __builtin_amdgcn_mfma_f32_16x16x32_f16(av, B0_[0], acc[m][0], 0, 0, 0); \
      acc[m][1] = __builtin_amdgcn_mfma_f32_16x16x32_f16(av, B0_[1], acc[m][1], 0, 0, 0); \
      acc[m][2] = __builtin_amdgcn_mfma_f32_16x16x32_f16(av, B0_[2], acc[m][2], 0, 0, 0); \
      acc[m][3] = __builtin_amdgcn_mfma_f32_16x16x32_f16(av, B0_[3], acc[m][3], 0, 0, 0); \
    }                                                                         \
    _Pragma("unroll")                                                         \
    for (int m = 0; m < MT; ++m) {                                            \
      f16x8 av = (f16x8)(hv1[m] * hh[m]);                                     \
      acc[m][0] = __builtin_amdgcn_mfma_f32_16x16x32_f16(av, B1_[0], acc[m][0], 0, 0, 0); \
      acc[m][1] = __builtin_amdgcn_mfma_f32_16x16x32_f16(av, B1_[1], acc[m][1], 0, 0, 0); \
      acc[m][2] = __builtin_amdgcn_mfma_f32_16x16x32_f16(av, B1_[2], acc[m][2], 0, 0, 0); \
      acc[m][3] = __builtin_amdgcn_mfma_f32_16x16x32_f16(av, B1_[3], acc[m][3], 0, 0, 0); \
    }                                                                         \
  }

#define COMPBIAS(B0_, B1_)                                                    \
  {                                                                           \
    _Pragma("unroll")                                                         \
    for (int m = 0; m < MT; ++m) {                                            \
      acc[m][0] = __builtin_amdgcn_mfma_f32_16x16x32_f16(hv0[m], B0_[0], acc[m][0], 0, 0, 0); \
      acc[m][1] = __builtin_amdgcn_mfma_f32_16x16x32_f16(hv0[m], B0_[1], acc[m][1], 0, 0, 0); \
      acc[m][2] = __builtin_amdgcn_mfma_f32_16x16x32_f16(hv0[m], B0_[2], acc[m][2], 0, 0, 0); \
      acc[m][3] = __builtin_amdgcn_mfma_f32_16x16x32_f16(hv0[m], B0_[3], acc[m][3], 0, 0, 0); \
    }                                                                         \
    _Pragma("unroll")                                                         \
    for (int m = 0; m < MT; ++m) {                                            \
      acc[m][0] = __builtin_amdgcn_mfma_f32_16x16x32_f16(hv1[m], B1_[0], acc[m][0], 0, 0, 0); \
      acc[m][1] = __builtin_amdgcn_mfma_f32_16x16x32_f16(hv1[m], B1_[1], acc[m][1], 0, 0, 0); \
      acc[m][2] = __builtin_amdgcn_mfma_f32_16x16x32_f16(hv1[m], B1_[2], acc[m][2], 0, 0, 0); \
      acc[m][3] = __builtin_amdgcn_mfma_f32_16x16x32_f16(hv1[m], B1_[3], acc[m][3], 0, 0, 0); \
    }                                                                         \
  }

  // ---- software-pipelined slice-pair loop: 2 pairs in flight, no barriers ----
  f16x8 pa0[4], pa1[4], pb0[4], pb1[4];
  LOADP(pa0, pa1, 0);
  LOADP(pb0, pb1, 1);
  #pragma unroll 1
  for (int p2 = 0; p2 < 32; ++p2) {
    COMPP(pa0, pa1, 2 * p2);
    LOADP(pa0, pa1, 2 * p2 + 2);            // p2=31 loads pair 64 = bias slices
    COMPP(pb0, pb1, 2 * p2 + 1);
    if (p2 < 31) LOADP(pb0, pb1, 2 * p2 + 3);
  }
  COMPBIAS(pa0, pa1);                        // pair 64 (slices 128,129)
#undef LOADP
#undef COMPP
#undef COMPBIAS

  // ---- epilogue: plain coalesced f32 msg stores (slot-ordered) ----
  #pragma unroll
  for (int m = 0; m < MT; ++m) {
    #pragma unroll
    for (int r = 0; r < 4; ++r) {
      int sl = e0 + wE + m * 16 + hi * 4 + r;
      float* row = msg + (size_t)sl * 64;
      #pragma unroll
      for (int n = 0; n < 4; ++n)
        row[n * 16 + l15] = acc[m][n][r];
    }
  }
}

// ---- fused segment-max + root transform + relu: 32 nodes/block ----
struct SegArgs {
  const float* msg0; const int* off0; const float* hold0; const float* rw0; const float* rb0;
  float* hnew0; int n0; int blk0;
  const float* msg1; const int* off1; const float* hold1; const float* rw1; const float* rb1;
  float* hnew1; int n1;
};

__global__ __launch_bounds__(256) void segfin2(SegArgs a) {
  int bid = blockIdx.x;
  int dir = (bid >= a.blk0) ? 1 : 0;
  int lb  = bid - (dir ? a.blk0 : 0);
  const float* msg  = dir ? a.msg1  : a.msg0;
  const int*   off  = dir ? a.off1  : a.off0;
  const float* hold = dir ? a.hold1 : a.hold0;
  const float* rw   = dir ? a.rw1   : a.rw0;
  const float* rb   = dir ? a.rb1   : a.rb0;
  float*       hnew = dir ? a.hnew1 : a.hnew0;
  int          n    = dir ? a.n1    : a.n0;

  __shared__ float s_w[64 * 64];
  __shared__ float s_b[64];
  int tid = threadIdx.x;
  for (int i = tid; i < 4096; i += 256) s_w[i] = rw[i];
  if (tid < 64) s_b[tid] = rb[tid];
  __syncthreads();
  int wave = tid >> 6, lane = tid & 63;
  #pragma unroll
  for (int it = 0; it < 8; ++it) {
    int node = lb * 32 + wave * 8 + it;
    if (node >= n) continue;

    int k0 = off[node], k1 = off[node + 1];
    float mx = -INFINITY;
    for (int k = k0; k < k1; ++k)
      mx = fmaxf(mx, msg[(size_t)k * 64 + lane]);
    if (k0 == k1) mx = 0.0f;          // isolated node -> 0 (PyG semantics)

    float v = hold[node * 64 + lane];
    float acc = s_b[lane];
    #pragma unroll 8
    for (int i = 0; i < 64; ++i)
      acc = fmaf(__shfl(v, i, 64), s_w[i * 64 + lane], acc);
    hnew[node * 64 + lane] = fmaxf(mx + acc, 0.0f);
  }
}

// ---- MFMA predictor head: 128 edges/block (4 waves x 32 edges) ----
__global__ __launch_bounds__(256) void head_mfma(
    const float* __restrict__ h_c, const float* __restrict__ h_t,
    const int* __restrict__ lsrc, const int* __restrict__ ldst,
    const float* __restrict__ lattr,
    const _Float16* __restrict__ headB,   // 8*2048 halves
    const float* __restrict__ w2, const float* __restrict__ b2,
    float* __restrict__ preds, float* __restrict__ logits, int nL)
{
  __shared__ __align__(16) _Float16 s_W[8][2048];     // 32KB
  __shared__ __align__(16) _Float16 s_z[4][32][ZSTR]; // wave-private rows
  __shared__ float s_w2[64];

  const int tid = threadIdx.x;
  const int wv = tid >> 6, lane = tid & 63;
  const int l15 = lane & 15, hi = lane >> 4;

  #pragma unroll
  for (int s = 0; s < 8; ++s)
    stage16(headB + s * 2048 + tid * 8, &s_W[s][tid * 8]);
  if (tid < 64) s_w2[tid] = w2[tid];
  const float b2v = b2[0];

  const int e0 = blockIdx.x * 128 + wv * 32;

  f16x8 ac[2][2], at[2][2], aa[2];
  #pragma unroll
  for (int m = 0; m < 2; ++m) {
    int e = e0 + m * 16 + l15;
    int ee = (e < nL) ? e : 0;
    const float* pc = h_c + (size_t)lsrc[ee] * 64;
    const float* pt = h_t + (size_t)ldst[ee] * 64;
    #pragma unroll
    for (int half = 0; half < 2; ++half) {
      float4 c0 = *(const float4*)(pc + half * 32 + hi * 8);
      float4 c1 = *(const float4*)(pc + half * 32 + hi * 8 + 4);
      float4 t0 = *(const float4*)(pt + half * 32 + hi * 8);
      float4 t1 = *(const float4*)(pt + half * 32 + hi * 8 + 4);
      ac[m][half] = (f16x8){(_Float16)c0.x,(_Float16)c0.y,(_Float16)c0.z,(_Float16)c0.w,
                            (_Float16)c1.x,(_Float16)c1.y,(_Float16)c1.z,(_Float16)c1.w};
      at[m][half] = (f16x8){(_Float16)t0.x,(_Float16)t0.y,(_Float16)t0.z,(_Float16)t0.w,
                            (_Float16)t1.x,(_Float16)t1.y,(_Float16)t1.z,(_Float16)t1.w};
    }
    f16x8 v = {};
    if (hi < 2) {
      float4 f0 = *(const float4*)(lattr + (size_t)ee * 16 + hi * 8);
      float4 f1 = *(const float4*)(lattr + (size_t)ee * 16 + hi * 8 + 4);
      v = (f16x8){(_Float16)f0.x,(_Float16)f0.y,(_Float16)f0.z,(_Float16)f0.w,
                  (_Float16)f1.x,(_Float16)f1.y,(_Float16)f1.z,(_Float16)f1.w};
    } else if (hi == 2) {
      v[0] = (_Float16)1.0f;   // krow 144 = bias
    }
    aa[m] = v;
  }

  __syncthreads();   // weights staged

  f32x4 acc1[2][4] = {};
  #pragma unroll
  for (int s = 0; s < 5; ++s) {
    f16x8 bfr[4];
    #pragma unroll
    for (int nn = 0; nn < 4; ++nn)
      bfr[nn] = *(const f16x8*)&s_W[s][(hi * 64 + nn * 16 + l15) * 8];
    #pragma unroll
    for (int m = 0; m < 2; ++m) {
      f16x8 a = (s == 0) ? ac[m][0] : (s == 1) ? ac[m][1]
              : (s == 2) ? at[m][0] : (s == 3) ? at[m][1] : aa[m];
      #pragma unroll
      for (int nn = 0; nn < 4; ++nn)
        acc1[m][nn] = __builtin_amdgcn_mfma_f32_16x16x32_f16(a, bfr[nn], acc1[m][nn], 0, 0, 0);
    }
  }

  #pragma unroll
  for (int m = 0; m < 2; ++m)
    #pragma unroll
    for (int nn = 0; nn < 4; ++nn)
      #pragma unroll
      for (int r = 0; r < 4; ++r)
        s_z[wv][m * 16 + hi * 4 + r][nn * 16 + l15] =
            (_Float16)fmaxf(acc1[m][nn][r], 0.0f);

  f16x8 abias = {};
  if (hi == 0) abias[0] = (_Float16)1.0f;   // krow2 64 = bias
  f32x4 acc2[2][4] = {};
  #pragma unroll
  for (int s = 0; s < 3; ++s) {
    f16x8 bfr[4];
    #pragma unroll
    for (int nn = 0; nn < 4; ++nn)
      bfr[nn] = *(const f16x8*)&s_W[5 + s][(hi * 64 + nn * 16 + l15) * 8];
    #pragma unroll
    for (int m = 0; m < 2; ++m) {
      f16x8 a = (s < 2) ? *(const f16x8*)&s_z[wv][m * 16 + l15][s * 32 + hi * 8] : abias;
      #pragma unroll
      for (int nn = 0; nn < 4; ++nn)
        acc2[m][nn] = __builtin_amdgcn_mfma_f32_16x16x32_f16(a, bfr[nn], acc2[m][nn], 0, 0, 0);
    }
  }

  #pragma unroll
  for (int m = 0; m < 2; ++m) {
    float part[4];
    #pragma unroll
    for (int r = 0; r < 4; ++r) {
      float p = 0.0f;
      #pragma unroll
      for (int nn = 0; nn < 4; ++nn)
        p = fmaf(fmaxf(acc2[m][nn][r], 0.0f), s_w2[nn * 16 + l15], p);
      part[r] = p;
    }
    #pragma unroll
    for (int off = 1; off < 16; off <<= 1) {
      #pragma unroll
      for (int r = 0; r < 4; ++r)
        part[r] += __shfl_xor(part[r], off, 64);
    }
    if (l15 == 0) {
      #pragma unroll
      for (int r = 0; r < 4; ++r) {
        int e = e0 + m * 16 + hi * 4 + r;
        if (e < nL) {
          float lg = part[r] + b2v;
          logits[e] = lg;
          preds[e]  = 1.0f / (1.0f + expf(-lg));
        }
      }
    }
  }
}

extern "C" void kernel_launch(void* const* d_in, const int* in_sizes, int n_in,
                              void* d_out, int out_size, void* d_ws, size_t ws_size,
                              hipStream_t stream) {
  const int*   x_c      = (const int*)  d_in[0];
  const int*   x_t      = (const int*)  d_in[1];
  const int*   esrc_ct  = (const int*)  d_in[2];
  const int*   edst_ct  = (const int*)  d_in[3];
  const int*   esrc_tc  = (const int*)  d_in[4];
  const int*   edst_tc  = (const int*)  d_in[5];
  const int*   lbl_src  = (const int*)  d_in[6];
  const int*   lbl_dst  = (const int*)  d_in[7];
  const float* eattr_ct = (const float*)d_in[8];
  const float* eattr_tc = (const float*)d_in[9];
  const float* lbl_attr = (const float*)d_in[10];
  const float* emb_c    = (const float*)d_in[11];
  const float* emb_t    = (const float*)d_in[12];
  const float* ntl_c_w  = (const float*)d_in[13];
  const float* ntl_c_b  = (const float*)d_in[14];
  const float* ntl_t_w  = (const float*)d_in[15];
  const float* ntl_t_b  = (const float*)d_in[16];
  const float* m1w      = (const float*)d_in[17];  // (2,2,16,64)
  const float* m1b      = (const float*)d_in[18];  // (2,2,64)
  const float* m2w      = (const float*)d_in[19];  // (2,2,64,4096)
  const float* m2b      = (const float*)d_in[20];  // (2,2,4096)
  const float* rw       = (const float*)d_in[21];  // (2,2,64,64)
  const float* rb       = (const float*)d_in[22];  // (2,2,64)
  const float* ph_w0    = (const float*)d_in[23];
  const float* ph_b0    = (const float*)d_in[24];
  const float* ph_w1    = (const float*)d_in[25];
  const float* ph_b1    = (const float*)d_in[26];
  const float* ph_w2    = (const float*)d_in[27];
  const float* ph_b2    = (const float*)d_in[28];

  float* out = (float*)d_out;

  // ---------------- workspace layout ----------------
  float* ws = (float*)d_ws;
  float* h_c0 = ws;                          // 320000
  float* h_c1 = h_c0 + NCN * 64;
  float* h_t0 = h_c1 + NCN * 64;             // 640000
  float* h_t1 = h_t0 + NTN * 64;
  float* msgT = h_t1 + NTN * 64;             // ESLOT*64 (ct -> target dst)
  float* msgC = msgT + (size_t)ESLOT * 64;   // ESLOT*64 (tc -> customer dst)
  _Float16* Bready  = (_Float16*)(msgC + (size_t)ESLOT * 64);  // 4*130*2048 h
  _Float16* m1ready = Bready + 4 * NSLICE * 2048;              // 4*2048 h
  _Float16* headBr  = m1ready + 4 * 2048;                      // 8*2048 h
  int* ip     = (int*)(headBr + 8 * 2048);
  int* offT   = ip;               ip += NTN + 1;
  int* offC   = ip;               ip += NCN + 1;
  // zeroed region start:
  int* cntT   = ip;               ip += NTN;
  int* cntC   = ip;               ip += NCN;
  int* curT   = ip;               ip += NTN;
  int* curC   = ip;               ip += NCN;
  int* permT  = ip;               ip += ESLOT;
  int* permC  = ip;               ip += ESLOT;
  size_t zero_bytes = (size_t)(2 * (NTN + NCN) + 2 * ESLOT) * sizeof(int);

  // ---------------- pipeline: 9 dispatches ----------------
  hipMemsetAsync(cntT, 0, zero_bytes, stream);
  count_edges<<<(2 * NEDGE + 255) / 256, 256, 0, stream>>>(edst_ct, edst_tc, cntT, cntC);

  // mega: scan (2 blocks, latency hidden) + weight prep + node transforms
  {
    MegaArgs ma;
    ma.cntT = cntT; ma.offT = offT; ma.cntC = cntC; ma.offC = offC;
    ma.m2w = m2w; ma.m2b = m2b; ma.outB = Bready;
    ma.m1w = m1w; ma.m1b = m1b; ma.outM1 = m1ready;
    ma.w0 = ph_w0; ma.b0 = ph_b0; ma.w1 = ph_w1; ma.b1 = ph_b1;
    ma.outHead = headBr;
    ma.emb0 = emb_c; ma.idx0 = x_c; ma.ntw0 = ntl_c_w; ma.ntb0 = ntl_c_b; ma.hout0 = h_c0;
    ma.emb1 = emb_t; ma.idx1 = x_t; ma.ntw1 = ntl_t_w; ma.ntb1 = ntl_t_b; ma.hout1 = h_t0;
    mega_pre<<<2 + PREPBLK + NTBLK, 256, 0, stream>>>(ma);
  }

  scatter_edges<<<(2 * NEDGE + 255) / 256, 256, 0, stream>>>(
      edst_ct, edst_tc, offT, offC, curT, curC, permT, permC);

  float* hc_cur = h_c0; float* hc_nxt = h_c1;
  float* ht_cur = h_t0; float* ht_nxt = h_t1;

  for (int l = 0; l < 2; ++l) {
    int p0 = l * 2 + 0;   // ct direction (writes to t)
    int p1 = l * 2 + 1;   // tc direction (writes to c)
    {
      ConvArgs ca;
      ca.h_src0 = hc_cur; ca.esrc0 = esrc_ct; ca.ea0 = eattr_ct; ca.perm0 = permT;
      ca.B0 = Bready + (size_t)p0 * NSLICE * 2048; ca.m10 = m1ready + (size_t)p0 * 2048;
      ca.msg0 = msgT;
      ca.h_src1 = ht_cur; ca.esrc1 = esrc_tc; ca.ea1 = eattr_tc; ca.perm1 = permC;
      ca.B1 = Bready + (size_t)p1 * NSLICE * 2048; ca.m11 = m1ready + (size_t)p1 * 2048;
      ca.msg1 = msgC;
      conv_stream<<<2 * EBLK, 128, 0, stream>>>(ca);
    }
    {
      SegArgs sg;
      sg.msg0 = msgT; sg.off0 = offT; sg.hold0 = ht_cur;
      sg.rw0 = rw + p0 * 4096; sg.rb0 = rb + p0 * 64; sg.hnew0 = ht_nxt;
      sg.n0 = NTN; sg.blk0 = (NTN + 31) / 32;
      sg.msg1 = msgC; sg.off1 = offC; sg.hold1 = hc_cur;
      sg.rw1 = rw + p1 * 4096; sg.rb1 = rb + p1 * 64; sg.hnew1 = hc_nxt;
      sg.n1 = NCN;
      segfin2<<<(NTN + 31) / 32 + (NCN + 31) / 32, 256, 0, stream>>>(sg);
    }
    float* t;
    t = hc_cur; hc_cur = hc_nxt; hc_nxt = t;
    t = ht_cur; ht_cur = ht_nxt; ht_nxt = t;
  }

  head_mfma<<<(NLBL + 127) / 128, 256, 0, stream>>>(
      hc_cur, ht_cur, lbl_src, lbl_dst, lbl_attr,
      headBr, ph_w2, ph_b2,
      out, out + NLBL, NLBL);
}

// Round 11
// 245.746 us; speedup vs baseline: 1.0559x; 1.0559x over previous
//
#include <hip/hip_runtime.h>
#include <hip/hip_bf16.h>
#include <math.h>

// ---------------- problem constants ----------------
#define NCN   5000      // customer nodes
#define NTN   10000     // target nodes
#define NEDGE 50000     // edges per direction
#define NLBL  20000     // label edges
#define EPB   128       // edges per block (2 waves x 4 M-tiles x 16)
#define EBLK  392       // blocks per direction (392*128 = 50176)
#define ESLOT 50176     // padded slots per direction
#define MT    4         // M-tiles per wave (64 edges/wave)

typedef _Float16 f16x8 __attribute__((ext_vector_type(8)));
typedef _Float16 f16x4 __attribute__((ext_vector_type(4)));
typedef float    f32x4 __attribute__((ext_vector_type(4)));

#define HSTRIDE 136          // halves per hidT row (128 edges + 8 pad)
#define NSLICE  130          // 128 m2w K-slices + 2 bias slices
#define ZSTR    72           // head z-buffer stride in halves

#define PREPBLK (4 * NSLICE + 4 + 8)          // 532
#define NTBLK   ((NCN + 31) / 32 + (NTN + 31) / 32)   // 157 + 313 = 470

__device__ __forceinline__ void stage16(const _Float16* g, _Float16* l) {
  __builtin_amdgcn_global_load_lds(
      (const __attribute__((address_space(1))) void*)g,
      (__attribute__((address_space(3))) void*)l, 16, 0, 0);
}

// ---------------- CSR count (edge lists are fixed inputs) ----------------
__global__ __launch_bounds__(256) void count_edges(
    const int* __restrict__ dT, const int* __restrict__ dC,
    int* __restrict__ cT, int* __restrict__ cC)
{
  int i = blockIdx.x * 256 + threadIdx.x;
  if (i < NEDGE) atomicAdd(&cT[dT[i]], 1);
  else { int j = i - NEDGE; if (j < NEDGE) atomicAdd(&cC[dC[j]], 1); }
}

// ---------------- mega pre-pass: scan (2 blks) + weight prep + node transform ----
struct MegaArgs {
  const int* cntT; int* offT; const int* cntC; int* offC;
  const float* m2w; const float* m2b; _Float16* outB;
  const float* m1w; const float* m1b; _Float16* outM1;
  const float* w0; const float* b0; const float* w1; const float* b1;
  _Float16* outHead;
  const float* emb0; const int* idx0; const float* ntw0; const float* ntb0; float* hout0;
  const float* emb1; const int* idx1; const float* ntw1; const float* ntb1; float* hout1;
};

__global__ __launch_bounds__(256) void mega_pre(MegaArgs a) {
  __shared__ float s_w[64 * 64];
  __shared__ float s_b[64];
  const int bid = blockIdx.x;
  const int t = threadIdx.x;

  if (bid < 2) {
    // ---- exclusive scan of counts -> offsets (off[n] = total), 256 threads ----
    int* lds = (int*)s_w;
    const int* c = bid ? a.cntC : a.cntT;
    int*       o = bid ? a.offC : a.offT;
    int        n = bid ? NCN : NTN;
    int CH = (n + 255) / 256;
    int base = t * CH;
    int s = 0;
    for (int i = 0; i < CH; ++i) { int idx = base + i; if (idx < n) s += c[idx]; }
    lds[t] = s;
    __syncthreads();
    for (int d = 1; d < 256; d <<= 1) {
      int v = (t >= d) ? lds[t - d] : 0;
      __syncthreads();
      lds[t] += v;
      __syncthreads();
    }
    int run = lds[t] - s;   // exclusive prefix
    for (int i = 0; i < CH; ++i) {
      int idx = base + i;
      if (idx < n) { o[idx] = run; run += c[idx]; }
    }
    if (t == 255) o[n] = lds[255];
    return;
  }

  if (bid < 2 + PREPBLK) {
    // ---- weight prep -> f16 fragment slices ----
    int pb = bid - 2;
    int hi = t >> 6, col = t & 63;
    f16x8 v;
    if (pb < 4 * NSLICE) {
      int p = pb / NSLICE, s = pb % NSLICE;
      const float* w  = a.m2w + p * 64 * 4096;
      const float* bb = a.m2b + p * 4096;
      #pragma unroll
      for (int j = 0; j < 8; ++j) {
        float x;
        if (s < 128) {
          int h = s >> 1, i = (s & 1) * 32 + hi * 8 + j;
          x = w[h * 4096 + i * 64 + col];
        } else {
          int i = (s - 128) * 32 + hi * 8 + j;
          x = bb[i * 64 + col];
        }
        v[j] = (_Float16)x;
      }
      *(f16x8*)(a.outB + ((size_t)(p * NSLICE + s)) * 2048 + t * 8) = v;
    } else if (pb < 4 * NSLICE + 4) {
      int p = pb - 4 * NSLICE;
      #pragma unroll
      for (int j = 0; j < 8; ++j) {
        int i = hi * 8 + j;
        float x = (i < 16) ? a.m1w[p * 1024 + i * 64 + col]
                : (i == 16) ? a.m1b[p * 64 + col] : 0.0f;
        v[j] = (_Float16)x;
      }
      *(f16x8*)(a.outM1 + (size_t)p * 2048 + t * 8) = v;
    } else {
      int s = pb - (4 * NSLICE + 4);
      #pragma unroll
      for (int j = 0; j < 8; ++j) {
        int k = hi * 8 + j;
        float x = 0.0f;
        if (s < 5) {
          int kr = s * 32 + k;
          x = (kr < 144) ? a.w0[kr * 64 + col] : (kr == 144 ? a.b0[col] : 0.0f);
        } else {
          int kr = (s - 5) * 32 + k;
          x = (kr < 64) ? a.w1[kr * 64 + col] : (kr == 64 ? a.b1[col] : 0.0f);
        }
        v[j] = (_Float16)x;
      }
      *(f16x8*)(a.outHead + (size_t)s * 2048 + t * 8) = v;
    }
    return;
  }

  // ---- node transform: 32 nodes/block ----
  {
    int nb  = bid - (2 + PREPBLK);
    int blk0 = (NCN + 31) / 32;
    int dir = (nb >= blk0) ? 1 : 0;
    int lb  = nb - (dir ? blk0 : 0);
    const float* emb = dir ? a.emb1 : a.emb0;
    const int*   idx = dir ? a.idx1 : a.idx0;
    const float* w   = dir ? a.ntw1 : a.ntw0;
    const float* b   = dir ? a.ntb1 : a.ntb0;
    float*       out = dir ? a.hout1 : a.hout0;
    int          n   = dir ? NTN : NCN;

    for (int i = t; i < 4096; i += 256) s_w[i] = w[i];
    if (t < 64) s_b[t] = b[t];
    __syncthreads();
    int wave = t >> 6, lane = t & 63;
    #pragma unroll
    for (int it = 0; it < 8; ++it) {
      int node = lb * 32 + wave * 8 + it;
      if (node >= n) continue;
      float v = emb[idx[node] * 64 + lane];
      float acc = s_b[lane];
      #pragma unroll 8
      for (int i = 0; i < 64; ++i)
        acc = fmaf(__shfl(v, i, 64), s_w[i * 64 + lane], acc);
      out[node * 64 + lane] = acc;
    }
  }
}

__global__ __launch_bounds__(256) void scatter_edges(
    const int* __restrict__ dT, const int* __restrict__ dC,
    const int* __restrict__ oT, const int* __restrict__ oC,
    int* __restrict__ curT, int* __restrict__ curC,
    int* __restrict__ permT, int* __restrict__ permC)
{
  int i = blockIdx.x * 256 + threadIdx.x;
  if (i < NEDGE) {
    int d = dT[i];
    int p = atomicAdd(&curT[d], 1);
    permT[oT[d] + p] = i;
  } else {
    int j = i - NEDGE;
    if (j < NEDGE) {
      int d = dC[j];
      int p = atomicAdd(&curC[d], 1);
      permC[oC[d] + p] = j;
    }
  }
}

// ---- streaming MFMA NNConv: B from L2 into registers, ZERO barriers ----
// 128 edges/block (2 waves x 4 M-tiles), 3-pair-deep register pipeline.
struct ConvArgs {
  const float* h_src0; const int* esrc0; const float* ea0;
  const int* perm0; const _Float16* B0; const _Float16* m10; float* msg0;
  const float* h_src1; const int* esrc1; const float* ea1;
  const int* perm1; const _Float16* B1; const _Float16* m11; float* msg1;
};

__global__ __launch_bounds__(128) void conv_stream(ConvArgs a) {
  __shared__ __align__(16) _Float16 s_hidT[64 * HSTRIDE];  // 17.4 KB, wave-private cols
  __shared__ int s_srcn[EPB];
  __shared__ int s_eidx[EPB];

  const int bid = blockIdx.x;
  const int dir = (bid >= EBLK) ? 1 : 0;
  const int eb  = bid - (dir ? EBLK : 0);

  const float*    h_src  = dir ? a.h_src1 : a.h_src0;
  const int*      esrc   = dir ? a.esrc1  : a.esrc0;
  const float*    eattr  = dir ? a.ea1    : a.ea0;
  const int*      eperm  = dir ? a.perm1  : a.perm0;
  const _Float16* Bready = dir ? a.B1     : a.B0;
  const _Float16* m1rdy  = dir ? a.m11    : a.m10;
  float*          msg    = dir ? a.msg1   : a.msg0;

  const int tid  = threadIdx.x;
  const int e0   = eb * EPB;
  const int w    = tid >> 6;
  const int lane = tid & 63;
  const int l15  = lane & 15;
  const int hi   = lane >> 4;
  const int wE   = w * 64;
  const int boff = (hi * 64 + l15) * 8;   // halves: lane's B-fragment offset

  // ---- idx gather (wave-private LDS region; no barrier needed) ----
  {
    int e = eperm[e0 + wE + lane];
    s_eidx[wE + lane] = e;
    s_srcn[wE + lane] = esrc[e];
  }

  // ---- gather hv into registers ----
  f16x8 hv0[MT], hv1[MT];
  #pragma unroll
  for (int m = 0; m < MT; ++m) {
    int el = wE + m * 16 + l15;
    const float* src = h_src + (size_t)s_srcn[el] * 64;
    float4 a0 = *(const float4*)(src + hi * 8);
    float4 a1 = *(const float4*)(src + hi * 8 + 4);
    float4 b0 = *(const float4*)(src + 32 + hi * 8);
    float4 b1 = *(const float4*)(src + 32 + hi * 8 + 4);
    hv0[m] = (f16x8){(_Float16)a0.x,(_Float16)a0.y,(_Float16)a0.z,(_Float16)a0.w,
                     (_Float16)a1.x,(_Float16)a1.y,(_Float16)a1.z,(_Float16)a1.w};
    hv1[m] = (f16x8){(_Float16)b0.x,(_Float16)b0.y,(_Float16)b0.z,(_Float16)b0.w,
                     (_Float16)b1.x,(_Float16)b1.y,(_Float16)b1.z,(_Float16)b1.w};
  }

  // ---- hidden = relu(eattr @ m1w + m1b), m1 B-frags direct from L2 ----
  {
    f16x8 ea[MT];
    #pragma unroll
    for (int m = 0; m < MT; ++m) {
      int e = s_eidx[wE + m * 16 + l15];
      f16x8 v = {};
      if (hi < 2) {
        float4 f0 = *(const float4*)(eattr + (size_t)e * 16 + hi * 8);
        float4 f1 = *(const float4*)(eattr + (size_t)e * 16 + hi * 8 + 4);
        v = (f16x8){(_Float16)f0.x,(_Float16)f0.y,(_Float16)f0.z,(_Float16)f0.w,
                    (_Float16)f1.x,(_Float16)f1.y,(_Float16)f1.z,(_Float16)f1.w};
      } else if (hi == 2) {
        v[0] = (_Float16)1.0f;    // i==16 -> bias row
      }
      ea[m] = v;
    }
    #pragma unroll
    for (int n = 0; n < 4; ++n) {
      f16x8 bm = *(const f16x8*)(m1rdy + n * 128 + boff);
      #pragma unroll
      for (int m = 0; m < MT; ++m) {
        f32x4 hacc = {};
        hacc = __builtin_amdgcn_mfma_f32_16x16x32_f16(ea[m], bm, hacc, 0, 0, 0);
        int h  = n * 16 + l15;
        int e4 = wE + m * 16 + hi * 4;
        f16x4 hval;
        #pragma unroll
        for (int r = 0; r < 4; ++r) hval[r] = (_Float16)fmaxf(hacc[r], 0.0f);
        *(f16x4*)&s_hidT[h * HSTRIDE + e4] = hval;   // wave-private columns
      }
    }
  }

  f32x4 acc[MT][4] = {};

#define LOADP(B0_, B1_, P_)                                                   \
  {                                                                           \
    const _Float16* p0 = Bready + (size_t)(2 * (P_)) * 2048 + boff;           \
    _Pragma("unroll")                                                         \
    for (int n = 0; n < 4; ++n) {                                             \
      B0_[n] = *(const f16x8*)(p0 + n * 128);                                 \
      B1_[n] = *(const f16x8*)(p0 + 2048 + n * 128);                          \
    }                                                                         \
  }

#define COMPP(B0_, B1_, P_)                                                   \
  {                                                                           \
    _Float16 hh[MT];                                                          \
    _Pragma("unroll")                                                         \
    for (int m = 0; m < MT; ++m)                                              \
      hh[m] = s_hidT[(P_) * HSTRIDE + wE + m * 16 + l15];                     \
    _Pragma("unroll")                                                         \
    for (int m = 0; m < MT; ++m) {                                            \
      f16x8 av = (f16x8)(hv0[m] * hh[m]);                                     \
      acc[m][0] = __builtin_amdgcn_mfma_f32_16x16x32_f16(av, B0_[0], acc[m][0], 0, 0, 0); \
      acc[m][1] = __builtin_amdgcn_mfma_f32_16x16x32_f16(av, B0_[1], acc[m][1], 0, 0, 0); \
      acc[m][2] = __builtin_amdgcn_mfma_f32_16x16x32_f16(av, B0_[2], acc[m][2], 0, 0, 0); \
      acc[m][3] = __builtin_amdgcn_mfma_f32_16x16x32_f16(av, B0_[3], acc[m][3], 0, 0, 0); \
    }                                                                         \
    _Pragma("unroll")                                                         \
    for (int m = 0; m < MT; ++m) {                                            \
      f16x8 av = (f16x8)(hv1[m] * hh[m]);                                     \
      acc[m][0] = __builtin_amdgcn_mfma_f32_16x16x32_f16(av, B1_[0], acc[m][0], 0, 0, 0); \
      acc[m][1] = __builtin_amdgcn_mfma_f32_16x16x32_f16(av, B1_[1], acc[m][1], 0, 0, 0); \
      acc[m][2] = __builtin_amdgcn_mfma_f32_16x16x32_f16(av, B1_[2], acc[m][2], 0, 0, 0); \
      acc[m][3] = __builtin_amdgcn_mfma_f32_16x16x32_f16(av, B1_[3], acc[m][3], 0, 0, 0); \
    }                                                                         \
  }

#define COMPBIAS(B0_, B1_)                                                    \
  {                                                                           \
    _Pragma("unroll")                                                         \
    for (int m = 0; m < MT; ++m) {                                            \
      acc[m][0] = __builtin_amdgcn_mfma_f32_16x16x32_f16(hv0[m], B0_[0], acc[m][0], 0, 0, 0); \
      acc[m][1] = __builtin_amdgcn_mfma_f32_16x16x32_f16(hv0[m], B0_[1], acc[m][1], 0, 0, 0); \
      acc[m][2] = __builtin_amdgcn_mfma_f32_16x16x32_f16(hv0[m], B0_[2], acc[m][2], 0, 0, 0); \
      acc[m][3] = __builtin_amdgcn_mfma_f32_16x16x32_f16(hv0[m], B0_[3], acc[m][3], 0, 0, 0); \
    }                                                                         \
    _Pragma("unroll")                                                         \
    for (int m = 0; m < MT; ++m) {                                            \
      acc[m][0] = __builtin_amdgcn_mfma_f32_16x16x32_f16(hv1[m], B1_[0], acc[m][0], 0, 0, 0); \
      acc[m][1] = __builtin_amdgcn_mfma_f32_16x16x32_f16(hv1[m], B1_[1], acc[m][1], 0, 0, 0); \
      acc[m][2] = __builtin_amdgcn_mfma_f32_16x16x32_f16(hv1[m], B1_[2], acc[m][2], 0, 0, 0); \
      acc[m][3] = __builtin_amdgcn_mfma_f32_16x16x32_f16(hv1[m], B1_[3], acc[m][3], 0, 0, 0); \
    }                                                                         \
  }

  // ---- 3-pair-deep software pipeline over 65 slice-pairs, no barriers ----
  // pairs 0..63 = m2w slices, pair 64 = bias slices (128,129).
  f16x8 pa0[4], pa1[4], pb0[4], pb1[4], pc0[4], pc1[4];
  LOADP(pa0, pa1, 0);
  LOADP(pb0, pb1, 1);
  LOADP(pc0, pc1, 2);
  #pragma unroll 1
  for (int p3 = 0; p3 < 20; ++p3) {        // pairs 0..59
    COMPP(pa0, pa1, 3 * p3);     LOADP(pa0, pa1, 3 * p3 + 3);
    COMPP(pb0, pb1, 3 * p3 + 1); LOADP(pb0, pb1, 3 * p3 + 4);
    COMPP(pc0, pc1, 3 * p3 + 2); LOADP(pc0, pc1, 3 * p3 + 5);  // max load = 62
  }
  COMPP(pa0, pa1, 60); LOADP(pa0, pa1, 63);
  COMPP(pb0, pb1, 61); LOADP(pb0, pb1, 64);
  COMPP(pc0, pc1, 62);
  COMPP(pa0, pa1, 63);
  COMPBIAS(pb0, pb1);                      // pair 64 (slices 128,129)
#undef LOADP
#undef COMPP
#undef COMPBIAS

  // ---- epilogue: plain coalesced f32 msg stores (slot-ordered) ----
  #pragma unroll
  for (int m = 0; m < MT; ++m) {
    #pragma unroll
    for (int r = 0; r < 4; ++r) {
      int sl = e0 + wE + m * 16 + hi * 4 + r;
      float* row = msg + (size_t)sl * 64;
      #pragma unroll
      for (int n = 0; n < 4; ++n)
        row[n * 16 + l15] = acc[m][n][r];
    }
  }
}

// ---- fused segment-max + root transform + relu: 32 nodes/block ----
struct SegArgs {
  const float* msg0; const int* off0; const float* hold0; const float* rw0; const float* rb0;
  float* hnew0; int n0; int blk0;
  const float* msg1; const int* off1; const float* hold1; const float* rw1; const float* rb1;
  float* hnew1; int n1;
};

__global__ __launch_bounds__(256) void segfin2(SegArgs a) {
  int bid = blockIdx.x;
  int dir = (bid >= a.blk0) ? 1 : 0;
  int lb  = bid - (dir ? a.blk0 : 0);
  const float* msg  = dir ? a.msg1  : a.msg0;
  const int*   off  = dir ? a.off1  : a.off0;
  const float* hold = dir ? a.hold1 : a.hold0;
  const float* rw   = dir ? a.rw1   : a.rw0;
  const float* rb   = dir ? a.rb1   : a.rb0;
  float*       hnew = dir ? a.hnew1 : a.hnew0;
  int          n    = dir ? a.n1    : a.n0;

  __shared__ float s_w[64 * 64];
  __shared__ float s_b[64];
  int tid = threadIdx.x;
  for (int i = tid; i < 4096; i += 256) s_w[i] = rw[i];
  if (tid < 64) s_b[tid] = rb[tid];
  __syncthreads();
  int wave = tid >> 6, lane = tid & 63;
  #pragma unroll
  for (int it = 0; it < 8; ++it) {
    int node = lb * 32 + wave * 8 + it;
    if (node >= n) continue;

    int k0 = off[node], k1 = off[node + 1];
    float mx = -INFINITY;
    for (int k = k0; k < k1; ++k)
      mx = fmaxf(mx, msg[(size_t)k * 64 + lane]);
    if (k0 == k1) mx = 0.0f;          // isolated node -> 0 (PyG semantics)

    float v = hold[node * 64 + lane];
    float acc = s_b[lane];
    #pragma unroll 8
    for (int i = 0; i < 64; ++i)
      acc = fmaf(__shfl(v, i, 64), s_w[i * 64 + lane], acc);
    hnew[node * 64 + lane] = fmaxf(mx + acc, 0.0f);
  }
}

// ---- MFMA predictor head: 128 edges/block (4 waves x 32 edges) ----
__global__ __launch_bounds__(256) void head_mfma(
    const float* __restrict__ h_c, const float* __restrict__ h_t,
    const int* __restrict__ lsrc, const int* __restrict__ ldst,
    const float* __restrict__ lattr,
    const _Float16* __restrict__ headB,   // 8*2048 halves
    const float* __restrict__ w2, const float* __restrict__ b2,
    float* __restrict__ preds, float* __restrict__ logits, int nL)
{
  __shared__ __align__(16) _Float16 s_W[8][2048];     // 32KB
  __shared__ __align__(16) _Float16 s_z[4][32][ZSTR]; // wave-private rows
  __shared__ float s_w2[64];

  const int tid = threadIdx.x;
  const int wv = tid >> 6, lane = tid & 63;
  const int l15 = lane & 15, hi = lane >> 4;

  #pragma unroll
  for (int s = 0; s < 8; ++s)
    stage16(headB + s * 2048 + tid * 8, &s_W[s][tid * 8]);
  if (tid < 64) s_w2[tid] = w2[tid];
  const float b2v = b2[0];

  const int e0 = blockIdx.x * 128 + wv * 32;

  f16x8 ac[2][2], at[2][2], aa[2];
  #pragma unroll
  for (int m = 0; m < 2; ++m) {
    int e = e0 + m * 16 + l15;
    int ee = (e < nL) ? e : 0;
    const float* pc = h_c + (size_t)lsrc[ee] * 64;
    const float* pt = h_t + (size_t)ldst[ee] * 64;
    #pragma unroll
    for (int half = 0; half < 2; ++half) {
      float4 c0 = *(const float4*)(pc + half * 32 + hi * 8);
      float4 c1 = *(const float4*)(pc + half * 32 + hi * 8 + 4);
      float4 t0 = *(const float4*)(pt + half * 32 + hi * 8);
      float4 t1 = *(const float4*)(pt + half * 32 + hi * 8 + 4);
      ac[m][half] = (f16x8){(_Float16)c0.x,(_Float16)c0.y,(_Float16)c0.z,(_Float16)c0.w,
                            (_Float16)c1.x,(_Float16)c1.y,(_Float16)c1.z,(_Float16)c1.w};
      at[m][half] = (f16x8){(_Float16)t0.x,(_Float16)t0.y,(_Float16)t0.z,(_Float16)t0.w,
                            (_Float16)t1.x,(_Float16)t1.y,(_Float16)t1.z,(_Float16)t1.w};
    }
    f16x8 v = {};
    if (hi < 2) {
      float4 f0 = *(const float4*)(lattr + (size_t)ee * 16 + hi * 8);
      float4 f1 = *(const float4*)(lattr + (size_t)ee * 16 + hi * 8 + 4);
      v = (f16x8){(_Float16)f0.x,(_Float16)f0.y,(_Float16)f0.z,(_Float16)f0.w,
                  (_Float16)f1.x,(_Float16)f1.y,(_Float16)f1.z,(_Float16)f1.w};
    } else if (hi == 2) {
      v[0] = (_Float16)1.0f;   // krow 144 = bias
    }
    aa[m] = v;
  }

  __syncthreads();   // weights staged

  f32x4 acc1[2][4] = {};
  #pragma unroll
  for (int s = 0; s < 5; ++s) {
    f16x8 bfr[4];
    #pragma unroll
    for (int nn = 0; nn < 4; ++nn)
      bfr[nn] = *(const f16x8*)&s_W[s][(hi * 64 + nn * 16 + l15) * 8];
    #pragma unroll
    for (int m = 0; m < 2; ++m) {
      f16x8 a = (s == 0) ? ac[m][0] : (s == 1) ? ac[m][1]
              : (s == 2) ? at[m][0] : (s == 3) ? at[m][1] : aa[m];
      #pragma unroll
      for (int nn = 0; nn < 4; ++nn)
        acc1[m][nn] = __builtin_amdgcn_mfma_f32_16x16x32_f16(a, bfr[nn], acc1[m][nn], 0, 0, 0);
    }
  }

  #pragma unroll
  for (int m = 0; m < 2; ++m)
    #pragma unroll
    for (int nn = 0; nn < 4; ++nn)
      #pragma unroll
      for (int r = 0; r < 4; ++r)
        s_z[wv][m * 16 + hi * 4 + r][nn * 16 + l15] =
            (_Float16)fmaxf(acc1[m][nn][r], 0.0f);

  f16x8 abias = {};
  if (hi == 0) abias[0] = (_Float16)1.0f;   // krow2 64 = bias
  f32x4 acc2[2][4] = {};
  #pragma unroll
  for (int s = 0; s < 3; ++s) {
    f16x8 bfr[4];
    #pragma unroll
    for (int nn = 0; nn < 4; ++nn)
      bfr[nn] = *(const f16x8*)&s_W[5 + s][(hi * 64 + nn * 16 + l15) * 8];
    #pragma unroll
    for (int m = 0; m < 2; ++m) {
      f16x8 a = (s < 2) ? *(const f16x8*)&s_z[wv][m * 16 + l15][s * 32 + hi * 8] : abias;
      #pragma unroll
      for (int nn = 0; nn < 4; ++nn)
        acc2[m][nn] = __builtin_amdgcn_mfma_f32_16x16x32_f16(a, bfr[nn], acc2[m][nn], 0, 0, 0);
    }
  }

  #pragma unroll
  for (int m = 0; m < 2; ++m) {
    float part[4];
    #pragma unroll
    for (int r = 0; r < 4; ++r) {
      float p = 0.0f;
      #pragma unroll
      for (int nn = 0; nn < 4; ++nn)
        p = fmaf(fmaxf(acc2[m][nn][r], 0.0f), s_w2[nn * 16 + l15], p);
      part[r] = p;
    }
    #pragma unroll
    for (int off = 1; off < 16; off <<= 1) {
      #pragma unroll
      for (int r = 0; r < 4; ++r)
        part[r] += __shfl_xor(part[r], off, 64);
    }
    if (l15 == 0) {
      #pragma unroll
      for (int r = 0; r < 4; ++r) {
        int e = e0 + m * 16 + hi * 4 + r;
        if (e < nL) {
          float lg = part[r] + b2v;
          logits[e] = lg;
          preds[e]  = 1.0f / (1.0f + expf(-lg));
        }
      }
    }
  }
}

extern "C" void kernel_launch(void* const* d_in, const int* in_sizes, int n_in,
                              void* d_out, int out_size, void* d_ws, size_t ws_size,
                              hipStream_t stream) {
  const int*   x_c      = (const int*)  d_in[0];
  const int*   x_t      = (const int*)  d_in[1];
  const int*   esrc_ct  = (const int*)  d_in[2];
  const int*   edst_ct  = (const int*)  d_in[3];
  const int*   esrc_tc  = (const int*)  d_in[4];
  const int*   edst_tc  = (const int*)  d_in[5];
  const int*   lbl_src  = (const int*)  d_in[6];
  const int*   lbl_dst  = (const int*)  d_in[7];
  const float* eattr_ct = (const float*)d_in[8];
  const float* eattr_tc = (const float*)d_in[9];
  const float* lbl_attr = (const float*)d_in[10];
  const float* emb_c    = (const float*)d_in[11];
  const float* emb_t    = (const float*)d_in[12];
  const float* ntl_c_w  = (const float*)d_in[13];
  const float* ntl_c_b  = (const float*)d_in[14];
  const float* ntl_t_w  = (const float*)d_in[15];
  const float* ntl_t_b  = (const float*)d_in[16];
  const float* m1w      = (const float*)d_in[17];  // (2,2,16,64)
  const float* m1b      = (const float*)d_in[18];  // (2,2,64)
  const float* m2w      = (const float*)d_in[19];  // (2,2,64,4096)
  const float* m2b      = (const float*)d_in[20];  // (2,2,4096)
  const float* rw       = (const float*)d_in[21];  // (2,2,64,64)
  const float* rb       = (const float*)d_in[22];  // (2,2,64)
  const float* ph_w0    = (const float*)d_in[23];
  const float* ph_b0    = (const float*)d_in[24];
  const float* ph_w1    = (const float*)d_in[25];
  const float* ph_b1    = (const float*)d_in[26];
  const float* ph_w2    = (const float*)d_in[27];
  const float* ph_b2    = (const float*)d_in[28];

  float* out = (float*)d_out;

  // ---------------- workspace layout ----------------
  float* ws = (float*)d_ws;
  float* h_c0 = ws;                          // 320000
  float* h_c1 = h_c0 + NCN * 64;
  float* h_t0 = h_c1 + NCN * 64;             // 640000
  float* h_t1 = h_t0 + NTN * 64;
  float* msgT = h_t1 + NTN * 64;             // ESLOT*64 (ct -> target dst)
  float* msgC = msgT + (size_t)ESLOT * 64;   // ESLOT*64 (tc -> customer dst)
  _Float16* Bready  = (_Float16*)(msgC + (size_t)ESLOT * 64);  // 4*130*2048 h
  _Float16* m1ready = Bready + 4 * NSLICE * 2048;              // 4*2048 h
  _Float16* headBr  = m1ready + 4 * 2048;                      // 8*2048 h
  int* ip     = (int*)(headBr + 8 * 2048);
  int* offT   = ip;               ip += NTN + 1;
  int* offC   = ip;               ip += NCN + 1;
  // zeroed region start:
  int* cntT   = ip;               ip += NTN;
  int* cntC   = ip;               ip += NCN;
  int* curT   = ip;               ip += NTN;
  int* curC   = ip;               ip += NCN;
  int* permT  = ip;               ip += ESLOT;
  int* permC  = ip;               ip += ESLOT;
  size_t zero_bytes = (size_t)(2 * (NTN + NCN) + 2 * ESLOT) * sizeof(int);

  // ---------------- pipeline: 9 dispatches ----------------
  hipMemsetAsync(cntT, 0, zero_bytes, stream);
  count_edges<<<(2 * NEDGE + 255) / 256, 256, 0, stream>>>(edst_ct, edst_tc, cntT, cntC);

  // mega: scan (2 blocks, latency hidden) + weight prep + node transforms
  {
    MegaArgs ma;
    ma.cntT = cntT; ma.offT = offT; ma.cntC = cntC; ma.offC = offC;
    ma.m2w = m2w; ma.m2b = m2b; ma.outB = Bready;
    ma.m1w = m1w; ma.m1b = m1b; ma.outM1 = m1ready;
    ma.w0 = ph_w0; ma.b0 = ph_b0; ma.w1 = ph_w1; ma.b1 = ph_b1;
    ma.outHead = headBr;
    ma.emb0 = emb_c; ma.idx0 = x_c; ma.ntw0 = ntl_c_w; ma.ntb0 = ntl_c_b; ma.hout0 = h_c0;
    ma.emb1 = emb_t; ma.idx1 = x_t; ma.ntw1 = ntl_t_w; ma.ntb1 = ntl_t_b; ma.hout1 = h_t0;
    mega_pre<<<2 + PREPBLK + NTBLK, 256, 0, stream>>>(ma);
  }

  scatter_edges<<<(2 * NEDGE + 255) / 256, 256, 0, stream>>>(
      edst_ct, edst_tc, offT, offC, curT, curC, permT, permC);

  float* hc_cur = h_c0; float* hc_nxt = h_c1;
  float* ht_cur = h_t0; float* ht_nxt = h_t1;

  for (int l = 0; l < 2; ++l) {
    int p0 = l * 2 + 0;   // ct direction (writes to t)
    int p1 = l * 2 + 1;   // tc direction (writes to c)
    {
      ConvArgs ca;
      ca.h_src0 = hc_cur; ca.esrc0 = esrc_ct; ca.ea0 = eattr_ct; ca.perm0 = permT;
      ca.B0 = Bready + (size_t)p0 * NSLICE * 2048; ca.m10 = m1ready + (size_t)p0 * 2048;
      ca.msg0 = msgT;
      ca.h_src1 = ht_cur; ca.esrc1 = esrc_tc; ca.ea1 = eattr_tc; ca.perm1 = permC;
      ca.B1 = Bready + (size_t)p1 * NSLICE * 2048; ca.m11 = m1ready + (size_t)p1 * 2048;
      ca.msg1 = msgC;
      conv_stream<<<2 * EBLK, 128, 0, stream>>>(ca);
    }
    {
      SegArgs sg;
      sg.msg0 = msgT; sg.off0 = offT; sg.hold0 = ht_cur;
      sg.rw0 = rw + p0 * 4096; sg.rb0 = rb + p0 * 64; sg.hnew0 = ht_nxt;
      sg.n0 = NTN; sg.blk0 = (NTN + 31) / 32;
      sg.msg1 = msgC; sg.off1 = offC; sg.hold1 = hc_cur;
      sg.rw1 = rw + p1 * 4096; sg.rb1 = rb + p1 * 64; sg.hnew1 = hc_nxt;
      sg.n1 = NCN;
      segfin2<<<(NTN + 31) / 32 + (NCN + 31) / 32, 256, 0, stream>>>(sg);
    }
    float* t;
    t = hc_cur; hc_cur = hc_nxt; hc_nxt = t;
    t = ht_cur; ht_cur = ht_nxt; ht_nxt = t;
  }

  head_mfma<<<(NLBL + 127) / 128, 256, 0, stream>>>(
      hc_cur, ht_cur, lbl_src, lbl_dst, lbl_attr,
      headBr, ph_w2, ph_b2,
      out, out + NLBL, NLBL);
}

// Round 12
// 238.469 us; speedup vs baseline: 1.0881x; 1.0305x over previous
//
#include <hip/hip_runtime.h>
#include <hip/hip_bf16.h>
#include <math.h>

// ---------------- problem constants ----------------
#define NCN   5000      // customer nodes
#define NTN   10000     // target nodes
#define NEDGE 50000     // edges per direction
#define NLBL  20000     // label edges
#define EPB   128       // edges per block (2 waves x 4 M-tiles x 16)
#define EBLK  392       // blocks per direction (392*128 = 50176)
#define ESLOT 50176     // padded slots per direction
#define MT    4         // M-tiles per wave (64 edges/wave)

typedef _Float16 f16x8 __attribute__((ext_vector_type(8)));
typedef _Float16 f16x4 __attribute__((ext_vector_type(4)));
typedef float    f32x4 __attribute__((ext_vector_type(4)));

#define HSTRIDE 136          // halves per hidT row (128 edges + 8 pad)
#define NSLICE  130          // 128 m2w K-slices + 2 bias slices
#define ZSTR    72           // head z-buffer stride in halves

#define PREPBLK (4 * NSLICE + 4 + 8)          // 532
#define NTBLK   ((NCN + 31) / 32 + (NTN + 31) / 32)   // 157 + 313 = 470

__device__ __forceinline__ void stage16(const _Float16* g, _Float16* l) {
  __builtin_amdgcn_global_load_lds(
      (const __attribute__((address_space(1))) void*)g,
      (__attribute__((address_space(3))) void*)l, 16, 0, 0);
}

// ---------------- CSR count (edge lists are fixed inputs) ----------------
__global__ __launch_bounds__(256) void count_edges(
    const int* __restrict__ dT, const int* __restrict__ dC,
    int* __restrict__ cT, int* __restrict__ cC)
{
  int i = blockIdx.x * 256 + threadIdx.x;
  if (i < NEDGE) atomicAdd(&cT[dT[i]], 1);
  else { int j = i - NEDGE; if (j < NEDGE) atomicAdd(&cC[dC[j]], 1); }
}

// ---------------- mega pre-pass: scan (2 blks) + weight prep + node transform ----
struct MegaArgs {
  const int* cntT; int* offT; const int* cntC; int* offC;
  const float* m2w; const float* m2b; _Float16* outB;
  const float* m1w; const float* m1b; _Float16* outM1;
  const float* w0; const float* b0; const float* w1; const float* b1;
  _Float16* outHead;
  const float* emb0; const int* idx0; const float* ntw0; const float* ntb0; float* hout0;
  const float* emb1; const int* idx1; const float* ntw1; const float* ntb1; float* hout1;
};

__global__ __launch_bounds__(256) void mega_pre(MegaArgs a) {
  __shared__ float s_w[64 * 64];
  __shared__ float s_b[64];
  const int bid = blockIdx.x;
  const int t = threadIdx.x;

  if (bid < 2) {
    // ---- exclusive scan of counts -> offsets (off[n] = total), 256 threads ----
    int* lds = (int*)s_w;
    const int* c = bid ? a.cntC : a.cntT;
    int*       o = bid ? a.offC : a.offT;
    int        n = bid ? NCN : NTN;
    int CH = (n + 255) / 256;
    int base = t * CH;
    int s = 0;
    for (int i = 0; i < CH; ++i) { int idx = base + i; if (idx < n) s += c[idx]; }
    lds[t] = s;
    __syncthreads();
    for (int d = 1; d < 256; d <<= 1) {
      int v = (t >= d) ? lds[t - d] : 0;
      __syncthreads();
      lds[t] += v;
      __syncthreads();
    }
    int run = lds[t] - s;   // exclusive prefix
    for (int i = 0; i < CH; ++i) {
      int idx = base + i;
      if (idx < n) { o[idx] = run; run += c[idx]; }
    }
    if (t == 255) o[n] = lds[255];
    return;
  }

  if (bid < 2 + PREPBLK) {
    // ---- weight prep -> f16 fragment slices ----
    int pb = bid - 2;
    int hi = t >> 6, col = t & 63;
    f16x8 v;
    if (pb < 4 * NSLICE) {
      int p = pb / NSLICE, s = pb % NSLICE;
      const float* w  = a.m2w + p * 64 * 4096;
      const float* bb = a.m2b + p * 4096;
      #pragma unroll
      for (int j = 0; j < 8; ++j) {
        float x;
        if (s < 128) {
          int h = s >> 1, i = (s & 1) * 32 + hi * 8 + j;
          x = w[h * 4096 + i * 64 + col];
        } else {
          int i = (s - 128) * 32 + hi * 8 + j;
          x = bb[i * 64 + col];
        }
        v[j] = (_Float16)x;
      }
      *(f16x8*)(a.outB + ((size_t)(p * NSLICE + s)) * 2048 + t * 8) = v;
    } else if (pb < 4 * NSLICE + 4) {
      int p = pb - 4 * NSLICE;
      #pragma unroll
      for (int j = 0; j < 8; ++j) {
        int i = hi * 8 + j;
        float x = (i < 16) ? a.m1w[p * 1024 + i * 64 + col]
                : (i == 16) ? a.m1b[p * 64 + col] : 0.0f;
        v[j] = (_Float16)x;
      }
      *(f16x8*)(a.outM1 + (size_t)p * 2048 + t * 8) = v;
    } else {
      int s = pb - (4 * NSLICE + 4);
      #pragma unroll
      for (int j = 0; j < 8; ++j) {
        int k = hi * 8 + j;
        float x = 0.0f;
        if (s < 5) {
          int kr = s * 32 + k;
          x = (kr < 144) ? a.w0[kr * 64 + col] : (kr == 144 ? a.b0[col] : 0.0f);
        } else {
          int kr = (s - 5) * 32 + k;
          x = (kr < 64) ? a.w1[kr * 64 + col] : (kr == 64 ? a.b1[col] : 0.0f);
        }
        v[j] = (_Float16)x;
      }
      *(f16x8*)(a.outHead + (size_t)s * 2048 + t * 8) = v;
    }
    return;
  }

  // ---- node transform: 32 nodes/block ----
  {
    int nb  = bid - (2 + PREPBLK);
    int blk0 = (NCN + 31) / 32;
    int dir = (nb >= blk0) ? 1 : 0;
    int lb  = nb - (dir ? blk0 : 0);
    const float* emb = dir ? a.emb1 : a.emb0;
    const int*   idx = dir ? a.idx1 : a.idx0;
    const float* w   = dir ? a.ntw1 : a.ntw0;
    const float* b   = dir ? a.ntb1 : a.ntb0;
    float*       out = dir ? a.hout1 : a.hout0;
    int          n   = dir ? NTN : NCN;

    for (int i = t; i < 4096; i += 256) s_w[i] = w[i];
    if (t < 64) s_b[t] = b[t];
    __syncthreads();
    int wave = t >> 6, lane = t & 63;
    #pragma unroll
    for (int it = 0; it < 8; ++it) {
      int node = lb * 32 + wave * 8 + it;
      if (node >= n) continue;
      float v = emb[idx[node] * 64 + lane];
      float acc = s_b[lane];
      #pragma unroll 8
      for (int i = 0; i < 64; ++i)
        acc = fmaf(__shfl(v, i, 64), s_w[i * 64 + lane], acc);
      out[node * 64 + lane] = acc;
    }
  }
}

__global__ __launch_bounds__(256) void scatter_edges(
    const int* __restrict__ dT, const int* __restrict__ dC,
    const int* __restrict__ oT, const int* __restrict__ oC,
    int* __restrict__ curT, int* __restrict__ curC,
    int* __restrict__ permT, int* __restrict__ permC)
{
  int i = blockIdx.x * 256 + threadIdx.x;
  if (i < NEDGE) {
    int d = dT[i];
    int p = atomicAdd(&curT[d], 1);
    permT[oT[d] + p] = i;
  } else {
    int j = i - NEDGE;
    if (j < NEDGE) {
      int d = dC[j];
      int p = atomicAdd(&curC[d], 1);
      permC[oC[d] + p] = j;
    }
  }
}

// ---- streaming MFMA NNConv: B from L2 into registers, ZERO barriers ----
// 128 edges/block (2 waves x 4 M-tiles), 2-pair register pipeline (R8 optimum).
struct ConvArgs {
  const float* h_src0; const int* esrc0; const float* ea0;
  const int* perm0; const _Float16* B0; const _Float16* m10; float* msg0;
  const float* h_src1; const int* esrc1; const float* ea1;
  const int* perm1; const _Float16* B1; const _Float16* m11; float* msg1;
};

__global__ __launch_bounds__(128) void conv_stream(ConvArgs a) {
  __shared__ __align__(16) _Float16 s_hidT[64 * HSTRIDE];  // 17.4 KB, wave-private cols
  __shared__ int s_srcn[EPB];
  __shared__ int s_eidx[EPB];

  const int bid = blockIdx.x;
  const int dir = (bid >= EBLK) ? 1 : 0;
  const int eb  = bid - (dir ? EBLK : 0);

  const float*    h_src  = dir ? a.h_src1 : a.h_src0;
  const int*      esrc   = dir ? a.esrc1  : a.esrc0;
  const float*    eattr  = dir ? a.ea1    : a.ea0;
  const int*      eperm  = dir ? a.perm1  : a.perm0;
  const _Float16* Bready = dir ? a.B1     : a.B0;
  const _Float16* m1rdy  = dir ? a.m11    : a.m10;
  float*          msg    = dir ? a.msg1   : a.msg0;

  const int tid  = threadIdx.x;
  const int e0   = eb * EPB;
  const int w    = tid >> 6;
  const int lane = tid & 63;
  const int l15  = lane & 15;
  const int hi   = lane >> 4;
  const int wE   = w * 64;
  const int boff = (hi * 64 + l15) * 8;   // halves: lane's B-fragment offset

  // ---- idx gather (wave-private LDS region; no barrier needed) ----
  {
    int e = eperm[e0 + wE + lane];
    s_eidx[wE + lane] = e;
    s_srcn[wE + lane] = esrc[e];
  }

  // ---- gather hv into registers ----
  f16x8 hv0[MT], hv1[MT];
  #pragma unroll
  for (int m = 0; m < MT; ++m) {
    int el = wE + m * 16 + l15;
    const float* src = h_src + (size_t)s_srcn[el] * 64;
    float4 a0 = *(const float4*)(src + hi * 8);
    float4 a1 = *(const float4*)(src + hi * 8 + 4);
    float4 b0 = *(const float4*)(src + 32 + hi * 8);
    float4 b1 = *(const float4*)(src + 32 + hi * 8 + 4);
    hv0[m] = (f16x8){(_Float16)a0.x,(_Float16)a0.y,(_Float16)a0.z,(_Float16)a0.w,
                     (_Float16)a1.x,(_Float16)a1.y,(_Float16)a1.z,(_Float16)a1.w};
    hv1[m] = (f16x8){(_Float16)b0.x,(_Float16)b0.y,(_Float16)b0.z,(_Float16)b0.w,
                     (_Float16)b1.x,(_Float16)b1.y,(_Float16)b1.z,(_Float16)b1.w};
  }

  // ---- hidden = relu(eattr @ m1w + m1b), m1 B-frags direct from L2 ----
  {
    f16x8 ea[MT];
    #pragma unroll
    for (int m = 0; m < MT; ++m) {
      int e = s_eidx[wE + m * 16 + l15];
      f16x8 v = {};
      if (hi < 2) {
        float4 f0 = *(const float4*)(eattr + (size_t)e * 16 + hi * 8);
        float4 f1 = *(const float4*)(eattr + (size_t)e * 16 + hi * 8 + 4);
        v = (f16x8){(_Float16)f0.x,(_Float16)f0.y,(_Float16)f0.z,(_Float16)f0.w,
                    (_Float16)f1.x,(_Float16)f1.y,(_Float16)f1.z,(_Float16)f1.w};
      } else if (hi == 2) {
        v[0] = (_Float16)1.0f;    // i==16 -> bias row
      }
      ea[m] = v;
    }
    #pragma unroll
    for (int n = 0; n < 4; ++n) {
      f16x8 bm = *(const f16x8*)(m1rdy + n * 128 + boff);
      #pragma unroll
      for (int m = 0; m < MT; ++m) {
        f32x4 hacc = {};
        hacc = __builtin_amdgcn_mfma_f32_16x16x32_f16(ea[m], bm, hacc, 0, 0, 0);
        int h  = n * 16 + l15;
        int e4 = wE + m * 16 + hi * 4;
        f16x4 hval;
        #pragma unroll
        for (int r = 0; r < 4; ++r) hval[r] = (_Float16)fmaxf(hacc[r], 0.0f);
        *(f16x4*)&s_hidT[h * HSTRIDE + e4] = hval;   // wave-private columns
      }
    }
  }

  f32x4 acc[MT][4] = {};

#define LOADP(B0_, B1_, P_)                                                   \
  {                                                                           \
    const _Float16* p0 = Bready + (size_t)(2 * (P_)) * 2048 + boff;           \
    _Pragma("unroll")                                                         \
    for (int n = 0; n < 4; ++n) {                                             \
      B0_[n] = *(const f16x8*)(p0 + n * 128);                                 \
      B1_[n] = *(const f16x8*)(p0 + 2048 + n * 128);                          \
    }                                                                         \
  }

#define COMPP(B0_, B1_, P_)                                                   \
  {                                                                           \
    _Float16 hh[MT];                                                          \
    _Pragma("unroll")                                                         \
    for (int m = 0; m < MT; ++m)                                              \
      hh[m] = s_hidT[(P_) * HSTRIDE + wE + m * 16 + l15];                     \
    _Pragma("unroll")                                                         \
    for (int m = 0; m < MT; ++m) {                                            \
      f16x8 av = (f16x8)(hv0[m] * hh[m]);                                     \
      acc[m][0] = __builtin_amdgcn_mfma_f32_16x16x32_f16(av, B0_[0], acc[m][0], 0, 0, 0); \
      acc[m][1] = __builtin_amdgcn_mfma_f32_16x16x32_f16(av, B0_[1], acc[m][1], 0, 0, 0); \
      acc[m][2] = __builtin_amdgcn_mfma_f32_16x16x32_f16(av, B0_[2], acc[m][2], 0, 0, 0); \
      acc[m][3] = __builtin_amdgcn_mfma_f32_16x16x32_f16(av, B0_[3], acc[m][3], 0, 0, 0); \
    }                                                                         \
    _Pragma("unroll")                                                         \
    for (int m = 0; m < MT; ++m) {                                            \
      f16x8 av = (f16x8)(hv1[m] * hh[m]);                                     \
      acc[m][0] = __builtin_amdgcn_mfma_f32_16x16x32_f16(av, B1_[0], acc[m][0], 0, 0, 0); \
      acc[m][1] = __builtin_amdgcn_mfma_f32_16x16x32_f16(av, B1_[1], acc[m][1], 0, 0, 0); \
      acc[m][2] = __builtin_amdgcn_mfma_f32_16x16x32_f16(av, B1_[2], acc[m][2], 0, 0, 0); \
      acc[m][3] = __builtin_amdgcn_mfma_f32_16x16x32_f16(av, B1_[3], acc[m][3], 0, 0, 0); \
    }                                                                         \
  }

#define COMPBIAS(B0_, B1_)                                                    \
  {                                                                           \
    _Pragma("unroll")                                                         \
    for (int m = 0; m < MT; ++m) {                                            \
      acc[m][0] = __builtin_amdgcn_mfma_f32_16x16x32_f16(hv0[m], B0_[0], acc[m][0], 0, 0, 0); \
      acc[m][1] = __builtin_amdgcn_mfma_f32_16x16x32_f16(hv0[m], B0_[1], acc[m][1], 0, 0, 0); \
      acc[m][2] = __builtin_amdgcn_mfma_f32_16x16x32_f16(hv0[m], B0_[2], acc[m][2], 0, 0, 0); \
      acc[m][3] = __builtin_amdgcn_mfma_f32_16x16x32_f16(hv0[m], B0_[3], acc[m][3], 0, 0, 0); \
    }                                                                         \
    _Pragma("unroll")                                                         \
    for (int m = 0; m < MT; ++m) {                                            \
      acc[m][0] = __builtin_amdgcn_mfma_f32_16x16x32_f16(hv1[m], B1_[0], acc[m][0], 0, 0, 0); \
      acc[m][1] = __builtin_amdgcn_mfma_f32_16x16x32_f16(hv1[m], B1_[1], acc[m][1], 0, 0, 0); \
      acc[m][2] = __builtin_amdgcn_mfma_f32_16x16x32_f16(hv1[m], B1_[2], acc[m][2], 0, 0, 0); \
      acc[m][3] = __builtin_amdgcn_mfma_f32_16x16x32_f16(hv1[m], B1_[3], acc[m][3], 0, 0, 0); \
    }                                                                         \
  }

  // ---- software-pipelined slice-pair loop: 2 pairs in flight, no barriers ----
  f16x8 pa0[4], pa1[4], pb0[4], pb1[4];
  LOADP(pa0, pa1, 0);
  LOADP(pb0, pb1, 1);
  #pragma unroll 1
  for (int p2 = 0; p2 < 32; ++p2) {
    COMPP(pa0, pa1, 2 * p2);
    LOADP(pa0, pa1, 2 * p2 + 2);            // p2=31 loads pair 64 = bias slices
    COMPP(pb0, pb1, 2 * p2 + 1);
    if (p2 < 31) LOADP(pb0, pb1, 2 * p2 + 3);
  }
  COMPBIAS(pa0, pa1);                        // pair 64 (slices 128,129)
#undef LOADP
#undef COMPP
#undef COMPBIAS

  // ---- epilogue: plain coalesced f32 msg stores (slot-ordered) ----
  #pragma unroll
  for (int m = 0; m < MT; ++m) {
    #pragma unroll
    for (int r = 0; r < 4; ++r) {
      int sl = e0 + wE + m * 16 + hi * 4 + r;
      float* row = msg + (size_t)sl * 64;
      #pragma unroll
      for (int n = 0; n < 4; ++n)
        row[n * 16 + l15] = acc[m][n][r];
    }
  }
}

// ---- fused segment-max + root transform + relu: 32 nodes/block ----
struct SegArgs {
  const float* msg0; const int* off0; const float* hold0; const float* rw0; const float* rb0;
  float* hnew0; int n0; int blk0;
  const float* msg1; const int* off1; const float* hold1; const float* rw1; const float* rb1;
  float* hnew1; int n1;
};

__global__ __launch_bounds__(256) void segfin2(SegArgs a) {
  int bid = blockIdx.x;
  int dir = (bid >= a.blk0) ? 1 : 0;
  int lb  = bid - (dir ? a.blk0 : 0);
  const float* msg  = dir ? a.msg1  : a.msg0;
  const int*   off  = dir ? a.off1  : a.off0;
  const float* hold = dir ? a.hold1 : a.hold0;
  const float* rw   = dir ? a.rw1   : a.rw0;
  const float* rb   = dir ? a.rb1   : a.rb0;
  float*       hnew = dir ? a.hnew1 : a.hnew0;
  int          n    = dir ? a.n1    : a.n0;

  __shared__ float s_w[64 * 64];
  __shared__ float s_b[64];
  int tid = threadIdx.x;
  for (int i = tid; i < 4096; i += 256) s_w[i] = rw[i];
  if (tid < 64) s_b[tid] = rb[tid];
  __syncthreads();
  int wave = tid >> 6, lane = tid & 63;
  #pragma unroll
  for (int it = 0; it < 8; ++it) {
    int node = lb * 32 + wave * 8 + it;
    if (node >= n) continue;

    int k0 = off[node], k1 = off[node + 1];
    float mx = -INFINITY;
    for (int k = k0; k < k1; ++k)
      mx = fmaxf(mx, msg[(size_t)k * 64 + lane]);
    if (k0 == k1) mx = 0.0f;          // isolated node -> 0 (PyG semantics)

    float v = hold[node * 64 + lane];
    float acc = s_b[lane];
    #pragma unroll 8
    for (int i = 0; i < 64; ++i)
      acc = fmaf(__shfl(v, i, 64), s_w[i * 64 + lane], acc);
    hnew[node * 64 + lane] = fmaxf(mx + acc, 0.0f);
  }
}

// ---- MFMA predictor head: 128 edges/block (4 waves x 32 edges) ----
__global__ __launch_bounds__(256) void head_mfma(
    const float* __restrict__ h_c, const float* __restrict__ h_t,
    const int* __restrict__ lsrc, const int* __restrict__ ldst,
    const float* __restrict__ lattr,
    const _Float16* __restrict__ headB,   // 8*2048 halves
    const float* __restrict__ w2, const float* __restrict__ b2,
    float* __restrict__ preds, float* __restrict__ logits, int nL)
{
  __shared__ __align__(16) _Float16 s_W[8][2048];     // 32KB
  __shared__ __align__(16) _Float16 s_z[4][32][ZSTR]; // wave-private rows
  __shared__ float s_w2[64];

  const int tid = threadIdx.x;
  const int wv = tid >> 6, lane = tid & 63;
  const int l15 = lane & 15, hi = lane >> 4;

  #pragma unroll
  for (int s = 0; s < 8; ++s)
    stage16(headB + s * 2048 + tid * 8, &s_W[s][tid * 8]);
  if (tid < 64) s_w2[tid] = w2[tid];
  const float b2v = b2[0];

  const int e0 = blockIdx.x * 128 + wv * 32;

  f16x8 ac[2][2], at[2][2], aa[2];
  #pragma unroll
  for (int m = 0; m < 2; ++m) {
    int e = e0 + m * 16 + l15;
    int ee = (e < nL) ? e : 0;
    const float* pc = h_c + (size_t)lsrc[ee] * 64;
    const float* pt = h_t + (size_t)ldst[ee] * 64;
    #pragma unroll
    for (int half = 0; half < 2; ++half) {
      float4 c0 = *(const float4*)(pc + half * 32 + hi * 8);
      float4 c1 = *(const float4*)(pc + half * 32 + hi * 8 + 4);
      float4 t0 = *(const float4*)(pt + half * 32 + hi * 8);
      float4 t1 = *(const float4*)(pt + half * 32 + hi * 8 + 4);
      ac[m][half] = (f16x8){(_Float16)c0.x,(_Float16)c0.y,(_Float16)c0.z,(_Float16)c0.w,
                            (_Float16)c1.x,(_Float16)c1.y,(_Float16)c1.z,(_Float16)c1.w};
      at[m][half] = (f16x8){(_Float16)t0.x,(_Float16)t0.y,(_Float16)t0.z,(_Float16)t0.w,
                            (_Float16)t1.x,(_Float16)t1.y,(_Float16)t1.z,(_Float16)t1.w};
    }
    f16x8 v = {};
    if (hi < 2) {
      float4 f0 = *(const float4*)(lattr + (size_t)ee * 16 + hi * 8);
      float4 f1 = *(const float4*)(lattr + (size_t)ee * 16 + hi * 8 + 4);
      v = (f16x8){(_Float16)f0.x,(_Float16)f0.y,(_Float16)f0.z,(_Float16)f0.w,
                  (_Float16)f1.x,(_Float16)f1.y,(_Float16)f1.z,(_Float16)f1.w};
    } else if (hi == 2) {
      v[0] = (_Float16)1.0f;   // krow 144 = bias
    }
    aa[m] = v;
  }

  __syncthreads();   // weights staged

  f32x4 acc1[2][4] = {};
  #pragma unroll
  for (int s = 0; s < 5; ++s) {
    f16x8 bfr[4];
    #pragma unroll
    for (int nn = 0; nn < 4; ++nn)
      bfr[nn] = *(const f16x8*)&s_W[s][(hi * 64 + nn * 16 + l15) * 8];
    #pragma unroll
    for (int m = 0; m < 2; ++m) {
      f16x8 a = (s == 0) ? ac[m][0] : (s == 1) ? ac[m][1]
              : (s == 2) ? at[m][0] : (s == 3) ? at[m][1] : aa[m];
      #pragma unroll
      for (int nn = 0; nn < 4; ++nn)
        acc1[m][nn] = __builtin_amdgcn_mfma_f32_16x16x32_f16(a, bfr[nn], acc1[m][nn], 0, 0, 0);
    }
  }

  #pragma unroll
  for (int m = 0; m < 2; ++m)
    #pragma unroll
    for (int nn = 0; nn < 4; ++nn)
      #pragma unroll
      for (int r = 0; r < 4; ++r)
        s_z[wv][m * 16 + hi * 4 + r][nn * 16 + l15] =
            (_Float16)fmaxf(acc1[m][nn][r], 0.0f);

  f16x8 abias = {};
  if (hi == 0) abias[0] = (_Float16)1.0f;   // krow2 64 = bias
  f32x4 acc2[2][4] = {};
  #pragma unroll
  for (int s = 0; s < 3; ++s) {
    f16x8 bfr[4];
    #pragma unroll
    for (int nn = 0; nn < 4; ++nn)
      bfr[nn] = *(const f16x8*)&s_W[5 + s][(hi * 64 + nn * 16 + l15) * 8];
    #pragma unroll
    for (int m = 0; m < 2; ++m) {
      f16x8 a = (s < 2) ? *(const f16x8*)&s_z[wv][m * 16 + l15][s * 32 + hi * 8] : abias;
      #pragma unroll
      for (int nn = 0; nn < 4; ++nn)
        acc2[m][nn] = __builtin_amdgcn_mfma_f32_16x16x32_f16(a, bfr[nn], acc2[m][nn], 0, 0, 0);
    }
  }

  #pragma unroll
  for (int m = 0; m < 2; ++m) {
    float part[4];
    #pragma unroll
    for (int r = 0; r < 4; ++r) {
      float p = 0.0f;
      #pragma unroll
      for (int nn = 0; nn < 4; ++nn)
        p = fmaf(fmaxf(acc2[m][nn][r], 0.0f), s_w2[nn * 16 + l15], p);
      part[r] = p;
    }
    #pragma unroll
    for (int off = 1; off < 16; off <<= 1) {
      #pragma unroll
      for (int r = 0; r < 4; ++r)
        part[r] += __shfl_xor(part[r], off, 64);
    }
    if (l15 == 0) {
      #pragma unroll
      for (int r = 0; r < 4; ++r) {
        int e = e0 + m * 16 + hi * 4 + r;
        if (e < nL) {
          float lg = part[r] + b2v;
          logits[e] = lg;
          preds[e]  = 1.0f / (1.0f + expf(-lg));
        }
      }
    }
  }
}

extern "C" void kernel_launch(void* const* d_in, const int* in_sizes, int n_in,
                              void* d_out, int out_size, void* d_ws, size_t ws_size,
                              hipStream_t stream) {
  const int*   x_c      = (const int*)  d_in[0];
  const int*   x_t      = (const int*)  d_in[1];
  const int*   esrc_ct  = (const int*)  d_in[2];
  const int*   edst_ct  = (const int*)  d_in[3];
  const int*   esrc_tc  = (const int*)  d_in[4];
  const int*   edst_tc  = (const int*)  d_in[5];
  const int*   lbl_src  = (const int*)  d_in[6];
  const int*   lbl_dst  = (const int*)  d_in[7];
  const float* eattr_ct = (const float*)d_in[8];
  const float* eattr_tc = (const float*)d_in[9];
  const float* lbl_attr = (const float*)d_in[10];
  const float* emb_c    = (const float*)d_in[11];
  const float* emb_t    = (const float*)d_in[12];
  const float* ntl_c_w  = (const float*)d_in[13];
  const float* ntl_c_b  = (const float*)d_in[14];
  const float* ntl_t_w  = (const float*)d_in[15];
  const float* ntl_t_b  = (const float*)d_in[16];
  const float* m1w      = (const float*)d_in[17];  // (2,2,16,64)
  const float* m1b      = (const float*)d_in[18];  // (2,2,64)
  const float* m2w      = (const float*)d_in[19];  // (2,2,64,4096)
  const float* m2b      = (const float*)d_in[20];  // (2,2,4096)
  const float* rw       = (const float*)d_in[21];  // (2,2,64,64)
  const float* rb       = (const float*)d_in[22];  // (2,2,64)
  const float* ph_w0    = (const float*)d_in[23];
  const float* ph_b0    = (const float*)d_in[24];
  const float* ph_w1    = (const float*)d_in[25];
  const float* ph_b1    = (const float*)d_in[26];
  const float* ph_w2    = (const float*)d_in[27];
  const float* ph_b2    = (const float*)d_in[28];

  float* out = (float*)d_out;

  // ---------------- workspace layout ----------------
  float* ws = (float*)d_ws;
  float* h_c0 = ws;                          // 320000
  float* h_c1 = h_c0 + NCN * 64;
  float* h_t0 = h_c1 + NCN * 64;             // 640000
  float* h_t1 = h_t0 + NTN * 64;
  float* msgT = h_t1 + NTN * 64;             // ESLOT*64 (ct -> target dst)
  float* msgC = msgT + (size_t)ESLOT * 64;   // ESLOT*64 (tc -> customer dst)
  _Float16* Bready  = (_Float16*)(msgC + (size_t)ESLOT * 64);  // 4*130*2048 h
  _Float16* m1ready = Bready + 4 * NSLICE * 2048;              // 4*2048 h
  _Float16* headBr  = m1ready + 4 * 2048;                      // 8*2048 h
  int* ip     = (int*)(headBr + 8 * 2048);
  int* offT   = ip;               ip += NTN + 1;
  int* offC   = ip;               ip += NCN + 1;
  // zeroed region start:
  int* cntT   = ip;               ip += NTN;
  int* cntC   = ip;               ip += NCN;
  int* curT   = ip;               ip += NTN;
  int* curC   = ip;               ip += NCN;
  int* permT  = ip;               ip += ESLOT;
  int* permC  = ip;               ip += ESLOT;
  size_t zero_bytes = (size_t)(2 * (NTN + NCN) + 2 * ESLOT) * sizeof(int);

  // ---------------- pipeline: 9 dispatches ----------------
  hipMemsetAsync(cntT, 0, zero_bytes, stream);
  count_edges<<<(2 * NEDGE + 255) / 256, 256, 0, stream>>>(edst_ct, edst_tc, cntT, cntC);

  // mega: scan (2 blocks, latency hidden) + weight prep + node transforms
  {
    MegaArgs ma;
    ma.cntT = cntT; ma.offT = offT; ma.cntC = cntC; ma.offC = offC;
    ma.m2w = m2w; ma.m2b = m2b; ma.outB = Bready;
    ma.m1w = m1w; ma.m1b = m1b; ma.outM1 = m1ready;
    ma.w0 = ph_w0; ma.b0 = ph_b0; ma.w1 = ph_w1; ma.b1 = ph_b1;
    ma.outHead = headBr;
    ma.emb0 = emb_c; ma.idx0 = x_c; ma.ntw0 = ntl_c_w; ma.ntb0 = ntl_c_b; ma.hout0 = h_c0;
    ma.emb1 = emb_t; ma.idx1 = x_t; ma.ntw1 = ntl_t_w; ma.ntb1 = ntl_t_b; ma.hout1 = h_t0;
    mega_pre<<<2 + PREPBLK + NTBLK, 256, 0, stream>>>(ma);
  }

  scatter_edges<<<(2 * NEDGE + 255) / 256, 256, 0, stream>>>(
      edst_ct, edst_tc, offT, offC, curT, curC, permT, permC);

  float* hc_cur = h_c0; float* hc_nxt = h_c1;
  float* ht_cur = h_t0; float* ht_nxt = h_t1;

  for (int l = 0; l < 2; ++l) {
    int p0 = l * 2 + 0;   // ct direction (writes to t)
    int p1 = l * 2 + 1;   // tc direction (writes to c)
    {
      ConvArgs ca;
      ca.h_src0 = hc_cur; ca.esrc0 = esrc_ct; ca.ea0 = eattr_ct; ca.perm0 = permT;
      ca.B0 = Bready + (size_t)p0 * NSLICE * 2048; ca.m10 = m1ready + (size_t)p0 * 2048;
      ca.msg0 = msgT;
      ca.h_src1 = ht_cur; ca.esrc1 = esrc_tc; ca.ea1 = eattr_tc; ca.perm1 = permC;
      ca.B1 = Bready + (size_t)p1 * NSLICE * 2048; ca.m11 = m1ready + (size_t)p1 * 2048;
      ca.msg1 = msgC;
      conv_stream<<<2 * EBLK, 128, 0, stream>>>(ca);
    }
    {
      SegArgs sg;
      sg.msg0 = msgT; sg.off0 = offT; sg.hold0 = ht_cur;
      sg.rw0 = rw + p0 * 4096; sg.rb0 = rb + p0 * 64; sg.hnew0 = ht_nxt;
      sg.n0 = NTN; sg.blk0 = (NTN + 31) / 32;
      sg.msg1 = msgC; sg.off1 = offC; sg.hold1 = hc_cur;
      sg.rw1 = rw + p1 * 4096; sg.rb1 = rb + p1 * 64; sg.hnew1 = hc_nxt;
      sg.n1 = NCN;
      segfin2<<<(NTN + 31) / 32 + (NCN + 31) / 32, 256, 0, stream>>>(sg);
    }
    float* t;
    t = hc_cur; hc_cur = hc_nxt; hc_nxt = t;
    t = ht_cur; ht_cur = ht_nxt; ht_nxt = t;
  }

  head_mfma<<<(NLBL + 127) / 128, 256, 0, stream>>>(
      hc_cur, ht_cur, lbl_src, lbl_dst, lbl_attr,
      headBr, ph_w2, ph_b2,
      out, out + NLBL, NLBL);
}